// Round 12
// baseline (241.057 us; speedup 1.0000x reference)
//
#include <hip/hip_runtime.h>
#include <hip/hip_bf16.h>

#define NB 32
#define DIN 512
#define TT 4096
#define DH 500
#define DHP 512
#define EPSV 1e-12f
#define BM 64
#define LDA 520            // bf16 elems; 1040B row stride, 16B-aligned rows
#define NTILES (TT / BM)   // 64 t-tiles per batch

typedef short short8 __attribute__((ext_vector_type(8)));
typedef float f32x16 __attribute__((ext_vector_type(16)));

__device__ inline unsigned short f2bf(float f) {
    unsigned int u = __builtin_bit_cast(unsigned int, f);
    unsigned int r = (u + 0x7fffu + ((u >> 16) & 1u)) >> 16;
    return (unsigned short)r;
}
__device__ inline float bf2f(unsigned short h) {
    unsigned int u = ((unsigned int)h) << 16;
    return __builtin_bit_cast(float, u);
}

// Kernel 0: pack w1 -> bf16 MFMA-fragment order [hb=16][ks=32][lane=64][8]
__global__ void prep_kernel(const float* __restrict__ w1, const float* __restrict__ w2,
                            unsigned short* __restrict__ w1b, float* __restrict__ w2f) {
    int idx = blockIdx.x * blockDim.x + threadIdx.x;
    if (idx < DHP * DIN) {
        const int j    = idx & 7;
        const int lane = (idx >> 3) & 63;
        const int ks   = (idx >> 9) & 31;
        const int hb   = idx >> 14;
        const int h = hb * 32 + (lane & 31);
        const int d = ks * 16 + (lane >> 5) * 8 + j;
        float v = (h < DH) ? w1[h * DIN + d] : 0.f;
        w1b[idx] = f2bf(v);
        if (idx < DHP) w2f[idx] = (idx < DH) ? w2[idx] : 0.f;
    }
}

// ABLATION: V bit0 = stage, bit1 = MFMA(+score reduce+softmax), bit2 = phase4.
// V=7 is the real R5 kernel (best known: 124 us total).
template<int V>
__launch_bounds__(512, 4)
__global__ void scores_fused(const float* __restrict__ x,
                             const unsigned short* __restrict__ w1b,
                             const float* __restrict__ w2f,
                             float* __restrict__ pm, float* __restrict__ pz,
                             float* __restrict__ pswx, float* __restrict__ psx,
                             float* __restrict__ psx2) {
    __shared__ unsigned short A_lds[BM][LDA];
    __shared__ float score_p[8][BM];
    __shared__ float w_lds[BM];

    const int tid = threadIdx.x;
    const int b = blockIdx.x >> 6;
    const int t0 = (blockIdx.x & 63) * BM;

    // ---- Phase 1: stage (R5 form: scalar loads, b128 row writes, 0 conflicts)
    if constexpr (V & 1) {
        const int ts = tid & 63;
        const int dg = tid >> 6;
        const float* xb = x + (size_t)b * DIN * TT + t0 + ts;
        #pragma unroll
        for (int oct = 0; oct < 8; ++oct) {
            const int d0 = dg * 64 + oct * 8;
            short8 pk;
            #pragma unroll
            for (int j = 0; j < 8; ++j)
                pk[j] = (short)f2bf(xb[(size_t)(d0 + j) * TT]);
            *reinterpret_cast<short8*>(&A_lds[ts][d0]) = pk;
        }
    }
    __syncthreads();
    if constexpr ((V & 1) && !(V & 2) && !(V & 4)) {
        // stage-only: keep LDS live (rule 17)
        unsigned short vr = A_lds[(tid + 7) & 63][(tid * 13) & 511];
        asm volatile("" :: "v"((int)vr));
    }

    if constexpr (V & 2) {
        // ---- Phase 2: MFMA ----
        const int w = tid >> 6;
        const int lane = tid & 63;
        const int lane31 = lane & 31;
        const int khalf = lane >> 5;
        const int hrow0 = w * 64;

        f32x16 acc00, acc01, acc10, acc11;
        #pragma unroll
        for (int g = 0; g < 16; ++g) { acc00[g] = 0.f; acc01[g] = 0.f; acc10[g] = 0.f; acc11[g] = 0.f; }

        const unsigned short* base0 = w1b + (size_t)w * 32768 + (size_t)lane * 8;
        const unsigned short* base1 = base0 + 16384;
        const unsigned short* Bp0 = &A_lds[lane31][khalf * 8];
        const unsigned short* Bp1 = &A_lds[32 + lane31][khalf * 8];

        #pragma unroll 4
        for (int ks = 0; ks < 32; ++ks) {
            short8 a0 = *reinterpret_cast<const short8*>(base0 + ks * 512);
            short8 a1 = *reinterpret_cast<const short8*>(base1 + ks * 512);
            short8 b0 = *reinterpret_cast<const short8*>(Bp0 + ks * 16);
            short8 b1 = *reinterpret_cast<const short8*>(Bp1 + ks * 16);
            acc00 = __builtin_amdgcn_mfma_f32_32x32x16_bf16(a0, b0, acc00, 0, 0, 0);
            acc01 = __builtin_amdgcn_mfma_f32_32x32x16_bf16(a0, b1, acc01, 0, 0, 0);
            acc10 = __builtin_amdgcn_mfma_f32_32x32x16_bf16(a1, b0, acc10, 0, 0, 0);
            acc11 = __builtin_amdgcn_mfma_f32_32x32x16_bf16(a1, b1, acc11, 0, 0, 0);
        }

        float s0 = 0.f, s1 = 0.f;
        #pragma unroll
        for (int g = 0; g < 16; ++g) {
            const int rp = (g & 3) + 8 * (g >> 2) + 4 * khalf;
            const float w20 = w2f[hrow0 + rp];
            const float w21 = w2f[hrow0 + 32 + rp];
            s0 += fmaxf(acc00[g], 0.f) * w20 + fmaxf(acc10[g], 0.f) * w21;
            s1 += fmaxf(acc01[g], 0.f) * w20 + fmaxf(acc11[g], 0.f) * w21;
        }
        s0 += __shfl_xor(s0, 32, 64);
        s1 += __shfl_xor(s1, 32, 64);
        if (khalf == 0) {
            score_p[w][lane31] = s0;
            score_p[w][32 + lane31] = s1;
        }
        __syncthreads();

        // ---- Phase 3: softmax partial ----
        if (tid < BM) {
            float s = 0.f;
            #pragma unroll
            for (int ww = 0; ww < 8; ++ww) s += score_p[ww][tid];
            float m = s;
            #pragma unroll
            for (int k = 1; k <= 32; k <<= 1) m = fmaxf(m, __shfl_xor(m, k, 64));
            float e = __expf(s - m);
            float Z = e;
            #pragma unroll
            for (int k = 1; k <= 32; k <<= 1) Z += __shfl_xor(Z, k, 64);
            w_lds[tid] = e;
            if (tid == 0) { pm[blockIdx.x] = m; pz[blockIdx.x] = Z; }
        }
        __syncthreads();
    } else if constexpr (V & 4) {
        if (tid < BM) w_lds[tid] = 1.0f;       // phase4 without softmax
        __syncthreads();
    }

    // ---- Phase 4: per-d partials ----
    if constexpr (V & 4) {
        const int d = tid;
        float sx = 0.f, sx2 = 0.f, swx = 0.f;
        #pragma unroll 8
        for (int t = 0; t < BM; ++t) {
            const float xv = bf2f(A_lds[t][d]);
            const float wv = w_lds[t];
            sx += xv; sx2 += xv * xv; swx += wv * xv;
        }
        const size_t o = (size_t)blockIdx.x * DHP + d;
        psx[o] = sx; psx2[o] = sx2; pswx[o] = swx;
    }
}

// Kernel 2: combine 64 tiles per batch -> mean, stddev
__global__ void combine_kernel(const float* __restrict__ pm, const float* __restrict__ pz,
                               const float* __restrict__ pswx, const float* __restrict__ psx,
                               const float* __restrict__ psx2, float* __restrict__ out) {
    __shared__ float sm[NTILES], sz[NTILES];
    const int b = blockIdx.x;
    const int tid = threadIdx.x;
    if (tid < NTILES) { sm[tid] = pm[b * NTILES + tid]; sz[tid] = pz[b * NTILES + tid]; }
    __syncthreads();

    float mg = -1e30f;
    #pragma unroll 8
    for (int i = 0; i < NTILES; ++i) mg = fmaxf(mg, sm[i]);
    float denom = 0.f;
    #pragma unroll 8
    for (int i = 0; i < NTILES; ++i) denom += sz[i] * __expf(sm[i] - mg);

    float num = 0.f, sx = 0.f, sx2 = 0.f;
    #pragma unroll 4
    for (int i = 0; i < NTILES; ++i) {
        const size_t o = ((size_t)(b * NTILES + i)) * DHP + tid;
        const float f = __expf(sm[i] - mg);
        num += f * pswx[o];
        sx  += psx[o];
        sx2 += psx2[o];
    }
    const float mean = num / denom;
    const float ex  = sx  * (1.f / TT);
    const float ex2 = sx2 * (1.f / TT);
    float var = ex2 - 2.f * mean * ex + mean * mean;
    if (var <= EPSV) var = EPSV;
    out[(size_t)b * 1024 + tid] = mean;
    out[(size_t)b * 1024 + 512 + tid] = sqrtf(var);
}

extern "C" void kernel_launch(void* const* d_in, const int* in_sizes, int n_in,
                              void* d_out, int out_size, void* d_ws, size_t ws_size,
                              hipStream_t stream) {
    const float* x  = (const float*)d_in[0];
    const float* w1 = (const float*)d_in[1];
    const float* w2 = (const float*)d_in[2];
    float* out = (float*)d_out;

    char* ws = (char*)d_ws;
    unsigned short* w1b = (unsigned short*)ws;                    // 512 KB
    float* w2f  = (float*)(ws + 524288);
    float* pm   = (float*)(ws + 526336);                          // 8 KB
    float* pz   = (float*)(ws + 534528);                          // 8 KB
    float* pswx = (float*)(ws + 542720);                          // 4 MB
    float* psx  = pswx + (size_t)NB * NTILES * DHP;
    float* psx2 = psx  + (size_t)NB * NTILES * DHP;

    // dummy outputs for ablation variants (far region of ws)
    char* dws = ws + (64u << 20);
    float* dpm   = (float*)dws;
    float* dpz   = dpm + NB * NTILES;
    float* dpswx = dpz + NB * NTILES;
    float* dpsx  = dpswx + (size_t)NB * NTILES * DHP;
    float* dpsx2 = dpsx  + (size_t)NB * NTILES * DHP;

    prep_kernel<<<(DHP * DIN + 255) / 256, 256, 0, stream>>>(w1, w2, w1b, w2f);
    // ablation dispatches (results unused):
    scores_fused<1><<<NB * NTILES, 512, 0, stream>>>(x, w1b, w2f, dpm, dpz, dpswx, dpsx, dpsx2);
    scores_fused<2><<<NB * NTILES, 512, 0, stream>>>(x, w1b, w2f, dpm, dpz, dpswx, dpsx, dpsx2);
    scores_fused<4><<<NB * NTILES, 512, 0, stream>>>(x, w1b, w2f, dpm, dpz, dpswx, dpsx, dpsx2);
    // real:
    scores_fused<7><<<NB * NTILES, 512, 0, stream>>>(x, w1b, w2f, pm, pz, pswx, psx, psx2);
    combine_kernel<<<NB, 512, 0, stream>>>(pm, pz, pswx, psx, psx2, out);
}

// Round 13
// 125.526 us; speedup vs baseline: 1.9204x; 1.9204x over previous
//
#include <hip/hip_runtime.h>
#include <hip/hip_bf16.h>

#define NB 32
#define DIN 512
#define TT 4096
#define DH 500
#define DHP 512
#define EPSV 1e-12f
#define BM 64
#define LDA 520            // bf16 elems; 1040B row stride, 16B-aligned rows
#define NTILES (TT / BM)   // 64 t-tiles per batch

typedef short short8 __attribute__((ext_vector_type(8)));
typedef float f32x16 __attribute__((ext_vector_type(16)));
typedef float f32x4 __attribute__((ext_vector_type(4)));

__device__ inline unsigned short f2bf(float f) {
    unsigned int u = __builtin_bit_cast(unsigned int, f);
    unsigned int r = (u + 0x7fffu + ((u >> 16) & 1u)) >> 16;
    return (unsigned short)r;
}
__device__ inline float bf2f(unsigned short h) {
    unsigned int u = ((unsigned int)h) << 16;
    return __builtin_bit_cast(float, u);
}

// Kernel 0: pack w1 -> bf16 MFMA-fragment order [hb=16][ks=32][lane=64][8]
//   h = hb*32 + (lane&31),  d = ks*16 + (lane>>5)*8 + j
__global__ void prep_kernel(const float* __restrict__ w1, const float* __restrict__ w2,
                            unsigned short* __restrict__ w1b, float* __restrict__ w2f) {
    int idx = blockIdx.x * blockDim.x + threadIdx.x;
    if (idx < DHP * DIN) {
        const int j    = idx & 7;
        const int lane = (idx >> 3) & 63;
        const int ks   = (idx >> 9) & 31;
        const int hb   = idx >> 14;
        const int h = hb * 32 + (lane & 31);
        const int d = ks * 16 + (lane >> 5) * 8 + j;
        float v = (h < DH) ? w1[h * DIN + d] : 0.f;
        w1b[idx] = f2bf(v);
        if (idx < DHP) w2f[idx] = (idx < DH) ? w2[idx] : 0.f;
    }
}

// Kernel 1 (fused): per (b, 64-t tile): scores -> softmax partial -> per-d
// partials. Tail redesigned: all-wave register softmax (shfl, no barriers),
// phase4 with b128 LDS reads + __shfl(e,t) + shfl-tree reduce.
__launch_bounds__(512, 2)
__global__ void scores_fused(const float* __restrict__ x,
                             const unsigned short* __restrict__ w1b,
                             const float* __restrict__ w2f,
                             float* __restrict__ pm, float* __restrict__ pz,
                             float* __restrict__ pswx, float* __restrict__ psx,
                             float* __restrict__ psx2) {
    __shared__ unsigned short A_lds[BM][LDA];
    __shared__ float score_p[8][BM];

    const int tid = threadIdx.x;
    const int b = blockIdx.x >> 6;             // NTILES = 64 tiles per batch
    const int t0 = (blockIdx.x & 63) * BM;

    // ---- Phase 1: stage x[b, :, t0..t0+63] -> A_lds[t][d] (bf16) ----
    {
        const int ts = tid & 63;
        const int dg = tid >> 6;               // 0..7
        const float* xb = x + (size_t)b * DIN * TT + t0 + ts;
        #pragma unroll
        for (int oct = 0; oct < 8; ++oct) {
            const int d0 = dg * 64 + oct * 8;
            short8 pk;
            #pragma unroll
            for (int j = 0; j < 8; ++j)
                pk[j] = (short)f2bf(xb[(size_t)(d0 + j) * TT]);
            *reinterpret_cast<short8*>(&A_lds[ts][d0]) = pk;
        }
    }
    __syncthreads();

    // ---- Phase 2: MFMA. Wave w owns h-panels {2w,2w+1}; A=w1 (m=h),
    // B=x^T (n=t): D cols (lane&31)=t, rows=h -> relu*w2 reduce in-lane.
    const int w = tid >> 6;
    const int lane = tid & 63;
    const int lane31 = lane & 31;
    const int khalf = lane >> 5;
    const int hrow0 = w * 64;

    {
        f32x16 acc00, acc01, acc10, acc11;
        #pragma unroll
        for (int g = 0; g < 16; ++g) { acc00[g] = 0.f; acc01[g] = 0.f; acc10[g] = 0.f; acc11[g] = 0.f; }

        const unsigned short* base0 = w1b + (size_t)w * 32768 + (size_t)lane * 8;
        const unsigned short* base1 = base0 + 16384;
        const unsigned short* Bp0 = &A_lds[lane31][khalf * 8];
        const unsigned short* Bp1 = &A_lds[32 + lane31][khalf * 8];

        #pragma unroll 4
        for (int ks = 0; ks < 32; ++ks) {
            short8 a0 = *reinterpret_cast<const short8*>(base0 + ks * 512);
            short8 a1 = *reinterpret_cast<const short8*>(base1 + ks * 512);
            short8 b0 = *reinterpret_cast<const short8*>(Bp0 + ks * 16);
            short8 b1 = *reinterpret_cast<const short8*>(Bp1 + ks * 16);
            acc00 = __builtin_amdgcn_mfma_f32_32x32x16_bf16(a0, b0, acc00, 0, 0, 0);
            acc01 = __builtin_amdgcn_mfma_f32_32x32x16_bf16(a0, b1, acc01, 0, 0, 0);
            acc10 = __builtin_amdgcn_mfma_f32_32x32x16_bf16(a1, b0, acc10, 0, 0, 0);
            acc11 = __builtin_amdgcn_mfma_f32_32x32x16_bf16(a1, b1, acc11, 0, 0, 0);
        }

        float s0 = 0.f, s1 = 0.f;
        #pragma unroll
        for (int g = 0; g < 16; ++g) {
            const int rp = (g & 3) + 8 * (g >> 2) + 4 * khalf;
            const float w20 = w2f[hrow0 + rp];
            const float w21 = w2f[hrow0 + 32 + rp];
            s0 += fmaxf(acc00[g], 0.f) * w20 + fmaxf(acc10[g], 0.f) * w21;
            s1 += fmaxf(acc01[g], 0.f) * w20 + fmaxf(acc11[g], 0.f) * w21;
        }
        s0 += __shfl_xor(s0, 32, 64);
        s1 += __shfl_xor(s1, 32, 64);
        if (khalf == 0) {                      // deterministic per-wave partials
            score_p[w][lane31] = s0;
            score_p[w][32 + lane31] = s1;
        }
    }
    __syncthreads();

    // ---- Phase 3 (all waves, register-resident, barrier-free) ----
    // Each wave redundantly: s[lane] = sum_w score_p; wave-reduce m, Z.
    float e;
    {
        float s = 0.f;
        #pragma unroll
        for (int ww = 0; ww < 8; ++ww) s += score_p[ww][lane];
        float m = s;
        #pragma unroll
        for (int k = 1; k <= 32; k <<= 1) m = fmaxf(m, __shfl_xor(m, k, 64));
        e = __expf(s - m);
        float Z = e;
        #pragma unroll
        for (int k = 1; k <= 32; k <<= 1) Z += __shfl_xor(Z, k, 64);
        if (tid == 0) { pm[blockIdx.x] = m; pz[blockIdx.x] = Z; }
    }

    // ---- Phase 4: per-d partials; wave w owns d in [64w, 64w+64) ----
    // lane = (o = d-octet, g = t-group of 8): 8 b128 reads, e via shfl,
    // 3-round shfl-tree over g, f32x4 stores.
    {
        const int o = lane & 7;
        const int g = lane >> 3;
        const int d0 = w * 64 + o * 8;
        float sx8[8], sx28[8], swx8[8];
        #pragma unroll
        for (int e2 = 0; e2 < 8; ++e2) { sx8[e2] = 0.f; sx28[e2] = 0.f; swx8[e2] = 0.f; }
        #pragma unroll
        for (int t5 = 0; t5 < 8; ++t5) {
            const int t = g * 8 + t5;
            short8 xv8 = *reinterpret_cast<const short8*>(&A_lds[t][d0]);
            const float ee = __shfl(e, t, 64);
            #pragma unroll
            for (int e2 = 0; e2 < 8; ++e2) {
                const float f = bf2f((unsigned short)xv8[e2]);
                sx8[e2] += f; sx28[e2] += f * f; swx8[e2] += ee * f;
            }
        }
        #pragma unroll
        for (int mk = 8; mk <= 32; mk <<= 1) {
            #pragma unroll
            for (int e2 = 0; e2 < 8; ++e2) {
                sx8[e2]  += __shfl_xor(sx8[e2],  mk, 64);
                sx28[e2] += __shfl_xor(sx28[e2], mk, 64);
                swx8[e2] += __shfl_xor(swx8[e2], mk, 64);
            }
        }
        if (g == 0) {
            const size_t ob = (size_t)blockIdx.x * DHP + d0;
            f32x4 v0, v1;
            #pragma unroll
            for (int e2 = 0; e2 < 4; ++e2) { v0[e2] = sx8[e2]; v1[e2] = sx8[4 + e2]; }
            *reinterpret_cast<f32x4*>(&psx[ob]) = v0;
            *reinterpret_cast<f32x4*>(&psx[ob + 4]) = v1;
            #pragma unroll
            for (int e2 = 0; e2 < 4; ++e2) { v0[e2] = sx28[e2]; v1[e2] = sx28[4 + e2]; }
            *reinterpret_cast<f32x4*>(&psx2[ob]) = v0;
            *reinterpret_cast<f32x4*>(&psx2[ob + 4]) = v1;
            #pragma unroll
            for (int e2 = 0; e2 < 4; ++e2) { v0[e2] = swx8[e2]; v1[e2] = swx8[4 + e2]; }
            *reinterpret_cast<f32x4*>(&pswx[ob]) = v0;
            *reinterpret_cast<f32x4*>(&pswx[ob + 4]) = v1;
        }
    }
}

// Kernel 2: combine 64 tiles per batch -> mean, stddev
__global__ void combine_kernel(const float* __restrict__ pm, const float* __restrict__ pz,
                               const float* __restrict__ pswx, const float* __restrict__ psx,
                               const float* __restrict__ psx2, float* __restrict__ out) {
    __shared__ float sm[NTILES], sz[NTILES];
    const int b = blockIdx.x;
    const int tid = threadIdx.x;               // d = tid, 0..511
    if (tid < NTILES) { sm[tid] = pm[b * NTILES + tid]; sz[tid] = pz[b * NTILES + tid]; }
    __syncthreads();

    float mg = -1e30f;
    #pragma unroll 8
    for (int i = 0; i < NTILES; ++i) mg = fmaxf(mg, sm[i]);
    float denom = 0.f;
    #pragma unroll 8
    for (int i = 0; i < NTILES; ++i) denom += sz[i] * __expf(sm[i] - mg);

    float num = 0.f, sx = 0.f, sx2 = 0.f;
    #pragma unroll 4
    for (int i = 0; i < NTILES; ++i) {
        const size_t o = ((size_t)(b * NTILES + i)) * DHP + tid;
        const float f = __expf(sm[i] - mg);
        num += f * pswx[o];
        sx  += psx[o];
        sx2 += psx2[o];
    }
    const float mean = num / denom;
    const float ex  = sx  * (1.f / TT);
    const float ex2 = sx2 * (1.f / TT);
    float var = ex2 - 2.f * mean * ex + mean * mean;
    if (var <= EPSV) var = EPSV;
    out[(size_t)b * 1024 + tid] = mean;
    out[(size_t)b * 1024 + 512 + tid] = sqrtf(var);
}

extern "C" void kernel_launch(void* const* d_in, const int* in_sizes, int n_in,
                              void* d_out, int out_size, void* d_ws, size_t ws_size,
                              hipStream_t stream) {
    const float* x  = (const float*)d_in[0];
    const float* w1 = (const float*)d_in[1];
    const float* w2 = (const float*)d_in[2];
    float* out = (float*)d_out;

    char* ws = (char*)d_ws;
    unsigned short* w1b = (unsigned short*)ws;                    // 512 KB
    float* w2f  = (float*)(ws + 524288);                          // 2 KB
    float* pm   = (float*)(ws + 526336);                          // 8 KB
    float* pz   = (float*)(ws + 534528);                          // 8 KB
    float* pswx = (float*)(ws + 542720);                          // 4 MB
    float* psx  = pswx + (size_t)NB * NTILES * DHP;               // 4 MB
    float* psx2 = psx  + (size_t)NB * NTILES * DHP;               // 4 MB

    prep_kernel<<<(DHP * DIN + 255) / 256, 256, 0, stream>>>(w1, w2, w1b, w2f);
    scores_fused<<<NB * NTILES, 512, 0, stream>>>(x, w1b, w2f, pm, pz, pswx, psx, psx2);
    combine_kernel<<<NB, 512, 0, stream>>>(pm, pz, pswx, psx, psx2, out);
}